// Round 2
// baseline (285.074 us; speedup 1.0000x reference)
//
#include <hip/hip_runtime.h>

// LinearRNN as truncated FIR convolution:
//   y_t = sum_{i=0}^{32} G_i u_{t-i} + C A^t x0,   G_0 = D, G_i = C A^{i-1} B.
// R4:
//  k_conv: N-split waves. 512-thr blocks, 8 waves: rg=w>>1 owns 64 rows,
//    nhalf=w&1 owns 32 cols. acc[4][2]=32 + b=32 regs -> <=128 VGPR ->
//    __launch_bounds__(512,4): 4 waves/SIMD, 2 blocks/CU (R1 was 2/SIMD and
//    latency-bound: Mfma 25 / VALU 10 / HBM 12 / Occ 21, all idle).
//    Keeps R1's tap pairing (taps {j,j+16} share each ds_read, verified
//    bank-conflict = 0 with the (row&7)<<4 XOR swizzle).
//  k_prep: log-depth. A^2, A^4 via 2 barrier phases; seeds M_0..M_3 = C A^b;
//    4 independent per-wave chains M_{j+4} = M_j A^4 (11 steps, no barriers).
//    Serial depth 47 -> ~13.

#define T_LEN  262144
#define NTAP   33      // taps 0..32
#define ZLEN   48      // x0-correction horizon
#define ROWS   256     // output rows per conv block
#define HALO   32

typedef __attribute__((ext_vector_type(8))) short  short8;
typedef __attribute__((ext_vector_type(4))) short  short4v;
typedef __attribute__((ext_vector_type(4))) float  floatx4;

static __device__ __forceinline__ unsigned short f2bf(float f) {
    unsigned int x = __float_as_uint(f);
    x += 0x7fffu + ((x >> 16) & 1u);     // RNE (finite normals)
    return (unsigned short)(x >> 16);
}
static __device__ __forceinline__ float bf2f(unsigned short u) {
    return __uint_as_float(((unsigned int)u) << 16);
}

// ---------------------------------------------------------------------------
// K1 v2: log-depth prep. One block, 4 waves.
// pool slots: 0:An 1:At 2:Bt 3:E2n 4:E2t 5:E4t 6..9: M0..M3 (chain ping)
// Chain pong for wave w reuses pool[w] (An/At/Bt/E2n all dead by chain time:
// bA/bA2/bB/bE live in registers; extra barrier after reg loads prevents the
// pool[2]-write vs bB-read race).
// ---------------------------------------------------------------------------
__global__ __launch_bounds__(256, 1) void k_prep(
    const float* __restrict__ A, const float* __restrict__ B,
    const float* __restrict__ C, const float* __restrict__ D,
    const float* __restrict__ x0, unsigned short* __restrict__ gG,
    float* __restrict__ gZ)
{
    __shared__ unsigned short pool[10][64][72];   // 92,160 B
    const int tid = threadIdx.x;
    const int wv = tid >> 6, lane = tid & 63, l15 = lane & 15, q = lane >> 4;

    // phase 1: stage An, At, Bt, M0=C, G0=D
#pragma unroll
    for (int e = 0; e < 16; ++e) {
        int f = e * 256 + tid;
        int r = f >> 6, c = f & 63;
        unsigned short av = f2bf(A[f]);
        pool[0][r][c] = av;                // An
        pool[1][c][r] = av;                // At
        pool[2][c][r] = f2bf(B[f]);        // Bt
        pool[6][r][c] = f2bf(C[f]);        // M0 = C
        gG[f]         = f2bf(D[f]);        // G_0 = D
    }
    __syncthreads();

    float x0v[4];
#pragma unroll
    for (int nt = 0; nt < 4; ++nt) x0v[nt] = x0[l15 + 16 * nt];

    // phase 2: each wave owns rows [16wv,16wv+16) of: A2 = A*A, M1 = C*A
    {
        short8 bA[2][4];
#pragma unroll
        for (int kb = 0; kb < 2; ++kb)
#pragma unroll
            for (int nt = 0; nt < 4; ++nt)
                bA[kb][nt] = *(const short8*)&pool[1][l15 + 16*nt][kb*32 + q*8];

        short8 a0 = *(const short8*)&pool[0][16*wv + l15][q*8];
        short8 a1 = *(const short8*)&pool[0][16*wv + l15][32 + q*8];
#pragma unroll
        for (int nt = 0; nt < 4; ++nt) {
            floatx4 m = (floatx4){0.f, 0.f, 0.f, 0.f};
            m = __builtin_amdgcn_mfma_f32_16x16x32_bf16(a0, bA[0][nt], m, 0, 0, 0);
            m = __builtin_amdgcn_mfma_f32_16x16x32_bf16(a1, bA[1][nt], m, 0, 0, 0);
#pragma unroll
            for (int r = 0; r < 4; ++r) {
                unsigned short h = f2bf(m[r]);
                pool[3][16*wv + q*4 + r][l15 + 16*nt] = h;   // E2n
                pool[4][l15 + 16*nt][16*wv + q*4 + r] = h;   // E2t
            }
        }
        a0 = *(const short8*)&pool[6][16*wv + l15][q*8];
        a1 = *(const short8*)&pool[6][16*wv + l15][32 + q*8];
#pragma unroll
        for (int nt = 0; nt < 4; ++nt) {
            floatx4 m = (floatx4){0.f, 0.f, 0.f, 0.f};
            m = __builtin_amdgcn_mfma_f32_16x16x32_bf16(a0, bA[0][nt], m, 0, 0, 0);
            m = __builtin_amdgcn_mfma_f32_16x16x32_bf16(a1, bA[1][nt], m, 0, 0, 0);
#pragma unroll
            for (int r = 0; r < 4; ++r)
                pool[7][16*wv + q*4 + r][l15 + 16*nt] = f2bf(m[r]);   // M1
        }
    }
    __syncthreads();

    // phase 3: E4t = (A2*A2)^T slice; M2 = C*A2; M3 = M1*A2
    {
        short8 bA2[2][4];
#pragma unroll
        for (int kb = 0; kb < 2; ++kb)
#pragma unroll
            for (int nt = 0; nt < 4; ++nt)
                bA2[kb][nt] = *(const short8*)&pool[4][l15 + 16*nt][kb*32 + q*8];

        short8 a0 = *(const short8*)&pool[3][16*wv + l15][q*8];
        short8 a1 = *(const short8*)&pool[3][16*wv + l15][32 + q*8];
#pragma unroll
        for (int nt = 0; nt < 4; ++nt) {
            floatx4 m = (floatx4){0.f, 0.f, 0.f, 0.f};
            m = __builtin_amdgcn_mfma_f32_16x16x32_bf16(a0, bA2[0][nt], m, 0, 0, 0);
            m = __builtin_amdgcn_mfma_f32_16x16x32_bf16(a1, bA2[1][nt], m, 0, 0, 0);
#pragma unroll
            for (int r = 0; r < 4; ++r)
                pool[5][l15 + 16*nt][16*wv + q*4 + r] = f2bf(m[r]);   // E4t
        }
        a0 = *(const short8*)&pool[6][16*wv + l15][q*8];
        a1 = *(const short8*)&pool[6][16*wv + l15][32 + q*8];
#pragma unroll
        for (int nt = 0; nt < 4; ++nt) {
            floatx4 m = (floatx4){0.f, 0.f, 0.f, 0.f};
            m = __builtin_amdgcn_mfma_f32_16x16x32_bf16(a0, bA2[0][nt], m, 0, 0, 0);
            m = __builtin_amdgcn_mfma_f32_16x16x32_bf16(a1, bA2[1][nt], m, 0, 0, 0);
#pragma unroll
            for (int r = 0; r < 4; ++r)
                pool[8][16*wv + q*4 + r][l15 + 16*nt] = f2bf(m[r]);   // M2
        }
        a0 = *(const short8*)&pool[7][16*wv + l15][q*8];
        a1 = *(const short8*)&pool[7][16*wv + l15][32 + q*8];
#pragma unroll
        for (int nt = 0; nt < 4; ++nt) {
            floatx4 m = (floatx4){0.f, 0.f, 0.f, 0.f};
            m = __builtin_amdgcn_mfma_f32_16x16x32_bf16(a0, bA2[0][nt], m, 0, 0, 0);
            m = __builtin_amdgcn_mfma_f32_16x16x32_bf16(a1, bA2[1][nt], m, 0, 0, 0);
#pragma unroll
            for (int r = 0; r < 4; ++r)
                pool[9][16*wv + q*4 + r][l15 + 16*nt] = f2bf(m[r]);   // M3
        }
    }
    __syncthreads();

    // phase 4: operand regs for the chains
    short8 bE[2][4], bB[2][4];
#pragma unroll
    for (int kb = 0; kb < 2; ++kb)
#pragma unroll
        for (int nt = 0; nt < 4; ++nt) {
            bE[kb][nt] = *(const short8*)&pool[5][l15 + 16*nt][kb*32 + q*8];
            bB[kb][nt] = *(const short8*)&pool[2][l15 + 16*nt][kb*32 + q*8];
        }
    __syncthreads();   // pool[0..4] now reusable as chain pong buffers

    unsigned short (*cur)[72] = pool[6 + wv];
    unsigned short (*alt)[72] = pool[wv];

    // initial z_wv = M_wv x0 (bf16 LDS dot, same numerics as old z_0 path)
#pragma unroll
    for (int mt = 0; mt < 4; ++mt)
#pragma unroll
        for (int r = 0; r < 4; ++r) {
            float v = 0.f;
#pragma unroll
            for (int nt = 0; nt < 4; ++nt)
                v += bf2f(cur[16*mt + q*4 + r][l15 + 16*nt]) * x0v[nt];
            v += __shfl_xor(v, 1, 16); v += __shfl_xor(v, 2, 16);
            v += __shfl_xor(v, 4, 16); v += __shfl_xor(v, 8, 16);
            if (l15 == 0) gZ[wv*64 + 16*mt + q*4 + r] = v;
        }

    // chain: S_k = S_{k-1} * A^4, emitting G_{jm+1} (jm<32) and z_{4k+wv}
    for (int k = 1; k <= 11; ++k) {
        const int jm = 4*(k-1) + wv;     // cur = M_jm
        short8 a0[4], a1[4];
#pragma unroll
        for (int mt = 0; mt < 4; ++mt) {
            a0[mt] = *(const short8*)&cur[16*mt + l15][q*8];
            a1[mt] = *(const short8*)&cur[16*mt + l15][32 + q*8];
        }
        if (jm < 32) {                   // G_{jm+1} = M_jm * B
#pragma unroll
            for (int mt = 0; mt < 4; ++mt)
#pragma unroll
                for (int nt = 0; nt < 4; ++nt) {
                    floatx4 g = (floatx4){0.f, 0.f, 0.f, 0.f};
                    g = __builtin_amdgcn_mfma_f32_16x16x32_bf16(a0[mt], bB[0][nt], g, 0, 0, 0);
                    g = __builtin_amdgcn_mfma_f32_16x16x32_bf16(a1[mt], bB[1][nt], g, 0, 0, 0);
#pragma unroll
                    for (int r = 0; r < 4; ++r)
                        gG[(size_t)(jm+1)*4096 + (16*mt + q*4 + r)*64 + l15 + 16*nt] = f2bf(g[r]);
                }
        }
        floatx4 m[4][4];
#pragma unroll
        for (int mt = 0; mt < 4; ++mt)
#pragma unroll
            for (int nt = 0; nt < 4; ++nt) {
                m[mt][nt] = (floatx4){0.f, 0.f, 0.f, 0.f};
                m[mt][nt] = __builtin_amdgcn_mfma_f32_16x16x32_bf16(a0[mt], bE[0][nt], m[mt][nt], 0, 0, 0);
                m[mt][nt] = __builtin_amdgcn_mfma_f32_16x16x32_bf16(a1[mt], bE[1][nt], m[mt][nt], 0, 0, 0);
            }
#pragma unroll
        for (int mt = 0; mt < 4; ++mt)
#pragma unroll
            for (int nt = 0; nt < 4; ++nt)
#pragma unroll
                for (int r = 0; r < 4; ++r)
                    alt[16*mt + q*4 + r][l15 + 16*nt] = f2bf(m[mt][nt][r]);
        const int zi = 4*k + wv;
#pragma unroll
        for (int mt = 0; mt < 4; ++mt)
#pragma unroll
            for (int r = 0; r < 4; ++r) {
                float v = 0.f;
#pragma unroll
                for (int nt = 0; nt < 4; ++nt) v = fmaf(m[mt][nt][r], x0v[nt], v);
                v += __shfl_xor(v, 1, 16); v += __shfl_xor(v, 2, 16);
                v += __shfl_xor(v, 4, 16); v += __shfl_xor(v, 8, 16);
                if (l15 == 0) gZ[zi*64 + 16*mt + q*4 + r] = v;
            }
        unsigned short (*tmp)[72] = cur; cur = alt; alt = tmp;
    }
}

// ---------------------------------------------------------------------------
// K2 v2: N-split convolution. 512 thr = 8 waves; rg=w>>1 owns 64 rows,
// nhalf=w&1 owns cols [32*nhalf, 32*nhalf+32). acc[4 mt][2 nt].
// Tap pairing: a-frag(tap j, mt) == a-frag(tap j+16, mt+1); rt sweep 0..4
// gives 4 MFMA per ds_read in steady state. XOR swizzle (row&7)<<4 on write
// and read (R1-verified: SQ_LDS_BANK_CONFLICT = 0).
// Per wave: 528 MFMA, ~168 ds_read_b128, 8+ G loads per j from L2.
// ---------------------------------------------------------------------------
__global__ __launch_bounds__(512, 4) void k_conv(
    const float* __restrict__ u, const unsigned short* __restrict__ gG,
    const float* __restrict__ gZ, float* __restrict__ out)
{
    __shared__ __align__(16) unsigned char uS[(ROWS + HALO) * 128];  // 36,864 B
    const int tid = threadIdx.x;
    const int wv = tid >> 6, lane = tid & 63, l15 = lane & 15, q = lane >> 4;
    const int nhalf = wv & 1, rg = wv >> 1;
    const int t0 = blockIdx.x * ROWS;

    // stage u rows [t0-32, t0+256) as bf16 (rows < 0 -> zeros, block 0 only)
    {
        const float4* u4 = (const float4*)u;
        const int base4 = (t0 - HALO) * 16;     // float4 index of first staged row
#pragma unroll
        for (int e = 0; e < 9; ++e) {
            int f = e * 512 + tid;              // 4608 float4 total
            float4 v = make_float4(0.f, 0.f, 0.f, 0.f);
            if (base4 + f >= 0) v = u4[base4 + f];
            int r  = f >> 4;                    // LDS row
            int cb = (f & 15) * 8;              // col byte (8 B granule, bit3 safe)
            short4v pk;
            pk[0] = (short)f2bf(v.x); pk[1] = (short)f2bf(v.y);
            pk[2] = (short)f2bf(v.z); pk[3] = (short)f2bf(v.w);
            *(short4v*)(uS + (r * 128 + (cb ^ ((r & 7) << 4)))) = pk;
        }
    }
    __syncthreads();

    floatx4 acc[4][2];
#pragma unroll
    for (int mt = 0; mt < 4; ++mt)
#pragma unroll
        for (int nt = 0; nt < 2; ++nt) acc[mt][nt] = (floatx4){0.f, 0.f, 0.f, 0.f};

    // main loop: tap groups {j, j+16}, j = 0..15
#pragma unroll 1
    for (int j = 0; j < 16; ++j) {
        short8 b0[2][2], b1[2][2];              // taps j, j+16 (b1 used first: rt=0)
#pragma unroll
        for (int kb = 0; kb < 2; ++kb)
#pragma unroll
            for (int nt = 0; nt < 2; ++nt) {
                const size_t off = (size_t)(l15 + 16*(2*nhalf + nt))*64 + kb*32 + q*8;
                b1[kb][nt] = *(const short8*)(gG + (size_t)(j + 16)*4096 + off);
                b0[kb][nt] = *(const short8*)(gG + (size_t)j*4096 + off);
            }
        // LDS row for (tap j+16k, mt): rg*64 + 16(mt-k) + 32 - j + l15,
        // rt = mt-k+1 in [0,4];  row&7 = (l15 - j) & 7  (group-invariant)
        const int swz  = ((l15 - j) & 7) << 4;
        const int rowb = (rg*64 + 16 - j + l15) * 128;
#pragma unroll
        for (int kb = 0; kb < 2; ++kb) {
            const int cb = (kb * 64 + q * 16) ^ swz;
#pragma unroll
            for (int rt = 0; rt <= 4; ++rt) {
                short8 a = *(const short8*)(uS + (rowb + rt * 2048 + cb));
                if (rt >= 1) {                  // tap j,   mt = rt-1
#pragma unroll
                    for (int nt = 0; nt < 2; ++nt)
                        acc[rt-1][nt] = __builtin_amdgcn_mfma_f32_16x16x32_bf16(
                            a, b0[kb][nt], acc[rt-1][nt], 0, 0, 0);
                }
                if (rt <= 3) {                  // tap j+16, mt = rt
#pragma unroll
                    for (int nt = 0; nt < 2; ++nt)
                        acc[rt][nt] = __builtin_amdgcn_mfma_f32_16x16x32_bf16(
                            a, b1[kb][nt], acc[rt][nt], 0, 0, 0);
                }
            }
        }
    }

    // tail: tap 32 (LDS row = rg*64 + 16mt + l15)
    {
        short8 bt[2][2];
#pragma unroll
        for (int kb = 0; kb < 2; ++kb)
#pragma unroll
            for (int nt = 0; nt < 2; ++nt)
                bt[kb][nt] = *(const short8*)(gG + (size_t)32*4096
                                  + (size_t)(l15 + 16*(2*nhalf + nt))*64 + kb*32 + q*8);
        const int swz  = (l15 & 7) << 4;
        const int rowb = (rg*64 + l15) * 128;
#pragma unroll
        for (int kb = 0; kb < 2; ++kb) {
            const int cb = (kb * 64 + q * 16) ^ swz;
#pragma unroll
            for (int mt = 0; mt < 4; ++mt) {
                short8 a = *(const short8*)(uS + (rowb + mt * 2048 + cb));
#pragma unroll
                for (int nt = 0; nt < 2; ++nt)
                    acc[mt][nt] = __builtin_amdgcn_mfma_f32_16x16x32_bf16(
                        a, bt[kb][nt], acc[mt][nt], 0, 0, 0);
            }
        }
    }

    // epilogue: row = rg*64 + 16mt + q*4 + r, col = 32*nhalf + 16nt + l15
    const bool zblk = (blockIdx.x == 0 && rg == 0);
#pragma unroll
    for (int mt = 0; mt < 4; ++mt)
#pragma unroll
        for (int nt = 0; nt < 2; ++nt) {
            const int p = l15 + 32*nhalf + 16*nt;
#pragma unroll
            for (int r = 0; r < 4; ++r) {
                int tl = rg*64 + mt*16 + q*4 + r;
                float v = acc[mt][nt][r];
                if (zblk && mt < 3) v += gZ[(mt*16 + q*4 + r)*64 + p];  // t < 48
                out[(size_t)(t0 + tl)*64 + p] = v;
            }
        }
}

extern "C" void kernel_launch(void* const* d_in, const int* in_sizes, int n_in,
                              void* d_out, int out_size, void* d_ws, size_t ws_size,
                              hipStream_t stream) {
    const float* u  = (const float*)d_in[0];
    const float* x0 = (const float*)d_in[1];
    const float* A  = (const float*)d_in[2];
    const float* B  = (const float*)d_in[3];
    const float* C  = (const float*)d_in[4];
    const float* D  = (const float*)d_in[5];
    float* out = (float*)d_out;

    unsigned short* gG = (unsigned short*)d_ws;                  // 33*4096 bf16 = 270 KB
    float* gZ = (float*)((char*)d_ws + 272384);                  // 48*64 fp32

    hipLaunchKernelGGL(k_prep, dim3(1), dim3(256), 0, stream,
                       A, B, C, D, x0, gG, gZ);
    hipLaunchKernelGGL(k_conv, dim3(T_LEN / ROWS), dim3(512), 0, stream,
                       u, gG, gZ, out);
}

// Round 3
// 279.329 us; speedup vs baseline: 1.0206x; 1.0206x over previous
//
#include <hip/hip_runtime.h>

// LinearRNN as truncated FIR convolution:
//   y_t = sum_{i=0}^{32} G_i u_{t-i} + C A^t x0,   G_0 = D, G_i = C A^{i-1} B.
// R5: R2 + cross-j software pipeline of the G (b-frag) loads.
//   Evidence trail: R0 (tap-dbuf G) Mfma 26.7 / R1 (no dbuf) 24.8 / R2
//   (no dbuf, 1/4 per-wave work) 19.1 -> the j-loop serializes on the L2
//   latency of the G loads at the top of each iteration. Fix: double-buffer
//   b-frags across j (unroll-2, static names), so the wait for j+1's G lands
//   after j's 32 MFMAs. Sweep body, swizzle, k_prep: UNCHANGED from R2.
//   Reg budget: acc 32 (AGPR) + 2x32 b-frags + ~16 temps ~= 112 < 128
//   -> keeps 4 waves/SIMD under __launch_bounds__(512,4).

#define T_LEN  262144
#define NTAP   33      // taps 0..32
#define ZLEN   48      // x0-correction horizon
#define ROWS   256     // output rows per conv block
#define HALO   32

typedef __attribute__((ext_vector_type(8))) short  short8;
typedef __attribute__((ext_vector_type(4))) short  short4v;
typedef __attribute__((ext_vector_type(4))) float  floatx4;

static __device__ __forceinline__ unsigned short f2bf(float f) {
    unsigned int x = __float_as_uint(f);
    x += 0x7fffu + ((x >> 16) & 1u);     // RNE (finite normals)
    return (unsigned short)(x >> 16);
}
static __device__ __forceinline__ float bf2f(unsigned short u) {
    return __uint_as_float(((unsigned int)u) << 16);
}

// ---------------------------------------------------------------------------
// K1: log-depth prep, UNCHANGED from R2 (passed, absmax 0.094).
// pool slots: 0:An 1:At 2:Bt 3:E2n 4:E2t 5:E4t 6..9: M0..M3 (chain ping)
// ---------------------------------------------------------------------------
__global__ __launch_bounds__(256, 1) void k_prep(
    const float* __restrict__ A, const float* __restrict__ B,
    const float* __restrict__ C, const float* __restrict__ D,
    const float* __restrict__ x0, unsigned short* __restrict__ gG,
    float* __restrict__ gZ)
{
    __shared__ unsigned short pool[10][64][72];   // 92,160 B
    const int tid = threadIdx.x;
    const int wv = tid >> 6, lane = tid & 63, l15 = lane & 15, q = lane >> 4;

#pragma unroll
    for (int e = 0; e < 16; ++e) {
        int f = e * 256 + tid;
        int r = f >> 6, c = f & 63;
        unsigned short av = f2bf(A[f]);
        pool[0][r][c] = av;                // An
        pool[1][c][r] = av;                // At
        pool[2][c][r] = f2bf(B[f]);        // Bt
        pool[6][r][c] = f2bf(C[f]);        // M0 = C
        gG[f]         = f2bf(D[f]);        // G_0 = D
    }
    __syncthreads();

    float x0v[4];
#pragma unroll
    for (int nt = 0; nt < 4; ++nt) x0v[nt] = x0[l15 + 16 * nt];

    // phase 2: A2 = A*A, M1 = C*A
    {
        short8 bA[2][4];
#pragma unroll
        for (int kb = 0; kb < 2; ++kb)
#pragma unroll
            for (int nt = 0; nt < 4; ++nt)
                bA[kb][nt] = *(const short8*)&pool[1][l15 + 16*nt][kb*32 + q*8];

        short8 a0 = *(const short8*)&pool[0][16*wv + l15][q*8];
        short8 a1 = *(const short8*)&pool[0][16*wv + l15][32 + q*8];
#pragma unroll
        for (int nt = 0; nt < 4; ++nt) {
            floatx4 m = (floatx4){0.f, 0.f, 0.f, 0.f};
            m = __builtin_amdgcn_mfma_f32_16x16x32_bf16(a0, bA[0][nt], m, 0, 0, 0);
            m = __builtin_amdgcn_mfma_f32_16x16x32_bf16(a1, bA[1][nt], m, 0, 0, 0);
#pragma unroll
            for (int r = 0; r < 4; ++r) {
                unsigned short h = f2bf(m[r]);
                pool[3][16*wv + q*4 + r][l15 + 16*nt] = h;   // E2n
                pool[4][l15 + 16*nt][16*wv + q*4 + r] = h;   // E2t
            }
        }
        a0 = *(const short8*)&pool[6][16*wv + l15][q*8];
        a1 = *(const short8*)&pool[6][16*wv + l15][32 + q*8];
#pragma unroll
        for (int nt = 0; nt < 4; ++nt) {
            floatx4 m = (floatx4){0.f, 0.f, 0.f, 0.f};
            m = __builtin_amdgcn_mfma_f32_16x16x32_bf16(a0, bA[0][nt], m, 0, 0, 0);
            m = __builtin_amdgcn_mfma_f32_16x16x32_bf16(a1, bA[1][nt], m, 0, 0, 0);
#pragma unroll
            for (int r = 0; r < 4; ++r)
                pool[7][16*wv + q*4 + r][l15 + 16*nt] = f2bf(m[r]);   // M1
        }
    }
    __syncthreads();

    // phase 3: E4t = (A2*A2)^T slice; M2 = C*A2; M3 = M1*A2
    {
        short8 bA2[2][4];
#pragma unroll
        for (int kb = 0; kb < 2; ++kb)
#pragma unroll
            for (int nt = 0; nt < 4; ++nt)
                bA2[kb][nt] = *(const short8*)&pool[4][l15 + 16*nt][kb*32 + q*8];

        short8 a0 = *(const short8*)&pool[3][16*wv + l15][q*8];
        short8 a1 = *(const short8*)&pool[3][16*wv + l15][32 + q*8];
#pragma unroll
        for (int nt = 0; nt < 4; ++nt) {
            floatx4 m = (floatx4){0.f, 0.f, 0.f, 0.f};
            m = __builtin_amdgcn_mfma_f32_16x16x32_bf16(a0, bA2[0][nt], m, 0, 0, 0);
            m = __builtin_amdgcn_mfma_f32_16x16x32_bf16(a1, bA2[1][nt], m, 0, 0, 0);
#pragma unroll
            for (int r = 0; r < 4; ++r)
                pool[5][l15 + 16*nt][16*wv + q*4 + r] = f2bf(m[r]);   // E4t
        }
        a0 = *(const short8*)&pool[6][16*wv + l15][q*8];
        a1 = *(const short8*)&pool[6][16*wv + l15][32 + q*8];
#pragma unroll
        for (int nt = 0; nt < 4; ++nt) {
            floatx4 m = (floatx4){0.f, 0.f, 0.f, 0.f};
            m = __builtin_amdgcn_mfma_f32_16x16x32_bf16(a0, bA2[0][nt], m, 0, 0, 0);
            m = __builtin_amdgcn_mfma_f32_16x16x32_bf16(a1, bA2[1][nt], m, 0, 0, 0);
#pragma unroll
            for (int r = 0; r < 4; ++r)
                pool[8][16*wv + q*4 + r][l15 + 16*nt] = f2bf(m[r]);   // M2
        }
        a0 = *(const short8*)&pool[7][16*wv + l15][q*8];
        a1 = *(const short8*)&pool[7][16*wv + l15][32 + q*8];
#pragma unroll
        for (int nt = 0; nt < 4; ++nt) {
            floatx4 m = (floatx4){0.f, 0.f, 0.f, 0.f};
            m = __builtin_amdgcn_mfma_f32_16x16x32_bf16(a0, bA2[0][nt], m, 0, 0, 0);
            m = __builtin_amdgcn_mfma_f32_16x16x32_bf16(a1, bA2[1][nt], m, 0, 0, 0);
#pragma unroll
            for (int r = 0; r < 4; ++r)
                pool[9][16*wv + q*4 + r][l15 + 16*nt] = f2bf(m[r]);   // M3
        }
    }
    __syncthreads();

    short8 bE[2][4], bB[2][4];
#pragma unroll
    for (int kb = 0; kb < 2; ++kb)
#pragma unroll
        for (int nt = 0; nt < 4; ++nt) {
            bE[kb][nt] = *(const short8*)&pool[5][l15 + 16*nt][kb*32 + q*8];
            bB[kb][nt] = *(const short8*)&pool[2][l15 + 16*nt][kb*32 + q*8];
        }
    __syncthreads();   // pool[0..4] now reusable as chain pong buffers

    unsigned short (*cur)[72] = pool[6 + wv];
    unsigned short (*alt)[72] = pool[wv];

#pragma unroll
    for (int mt = 0; mt < 4; ++mt)
#pragma unroll
        for (int r = 0; r < 4; ++r) {
            float v = 0.f;
#pragma unroll
            for (int nt = 0; nt < 4; ++nt)
                v += bf2f(cur[16*mt + q*4 + r][l15 + 16*nt]) * x0v[nt];
            v += __shfl_xor(v, 1, 16); v += __shfl_xor(v, 2, 16);
            v += __shfl_xor(v, 4, 16); v += __shfl_xor(v, 8, 16);
            if (l15 == 0) gZ[wv*64 + 16*mt + q*4 + r] = v;
        }

    for (int k = 1; k <= 11; ++k) {
        const int jm = 4*(k-1) + wv;     // cur = M_jm
        short8 a0[4], a1[4];
#pragma unroll
        for (int mt = 0; mt < 4; ++mt) {
            a0[mt] = *(const short8*)&cur[16*mt + l15][q*8];
            a1[mt] = *(const short8*)&cur[16*mt + l15][32 + q*8];
        }
        if (jm < 32) {                   // G_{jm+1} = M_jm * B
#pragma unroll
            for (int mt = 0; mt < 4; ++mt)
#pragma unroll
                for (int nt = 0; nt < 4; ++nt) {
                    floatx4 g = (floatx4){0.f, 0.f, 0.f, 0.f};
                    g = __builtin_amdgcn_mfma_f32_16x16x32_bf16(a0[mt], bB[0][nt], g, 0, 0, 0);
                    g = __builtin_amdgcn_mfma_f32_16x16x32_bf16(a1[mt], bB[1][nt], g, 0, 0, 0);
#pragma unroll
                    for (int r = 0; r < 4; ++r)
                        gG[(size_t)(jm+1)*4096 + (16*mt + q*4 + r)*64 + l15 + 16*nt] = f2bf(g[r]);
                }
        }
        floatx4 m[4][4];
#pragma unroll
        for (int mt = 0; mt < 4; ++mt)
#pragma unroll
            for (int nt = 0; nt < 4; ++nt) {
                m[mt][nt] = (floatx4){0.f, 0.f, 0.f, 0.f};
                m[mt][nt] = __builtin_amdgcn_mfma_f32_16x16x32_bf16(a0[mt], bE[0][nt], m[mt][nt], 0, 0, 0);
                m[mt][nt] = __builtin_amdgcn_mfma_f32_16x16x32_bf16(a1[mt], bE[1][nt], m[mt][nt], 0, 0, 0);
            }
#pragma unroll
        for (int mt = 0; mt < 4; ++mt)
#pragma unroll
            for (int nt = 0; nt < 4; ++nt)
#pragma unroll
                for (int r = 0; r < 4; ++r)
                    alt[16*mt + q*4 + r][l15 + 16*nt] = f2bf(m[mt][nt][r]);
        const int zi = 4*k + wv;
#pragma unroll
        for (int mt = 0; mt < 4; ++mt)
#pragma unroll
            for (int r = 0; r < 4; ++r) {
                float v = 0.f;
#pragma unroll
                for (int nt = 0; nt < 4; ++nt) v = fmaf(m[mt][nt][r], x0v[nt], v);
                v += __shfl_xor(v, 1, 16); v += __shfl_xor(v, 2, 16);
                v += __shfl_xor(v, 4, 16); v += __shfl_xor(v, 8, 16);
                if (l15 == 0) gZ[zi*64 + 16*mt + q*4 + r] = v;
            }
        unsigned short (*tmp)[72] = cur; cur = alt; alt = tmp;
    }
}

// ---------------------------------------------------------------------------
// K2 v3: R2's N-split convolution + cross-j double-buffered G loads.
// 512 thr = 8 waves; rg=w>>1 owns 64 rows, nhalf=w&1 owns 32 cols.
// acc[4 mt][2 nt]. Tap pairing + XOR swizzle unchanged (conflicts = 0).
// ---------------------------------------------------------------------------
__global__ __launch_bounds__(512, 4) void k_conv(
    const float* __restrict__ u, const unsigned short* __restrict__ gG,
    const float* __restrict__ gZ, float* __restrict__ out)
{
    __shared__ __align__(16) unsigned char uS[(ROWS + HALO) * 128];  // 36,864 B
    const int tid = threadIdx.x;
    const int wv = tid >> 6, lane = tid & 63, l15 = lane & 15, q = lane >> 4;
    const int nhalf = wv & 1, rg = wv >> 1;
    const int t0 = blockIdx.x * ROWS;

    // stage u rows [t0-32, t0+256) as bf16 (rows < 0 -> zeros, block 0 only)
    {
        const float4* u4 = (const float4*)u;
        const int base4 = (t0 - HALO) * 16;     // float4 index of first staged row
#pragma unroll
        for (int e = 0; e < 9; ++e) {
            int f = e * 512 + tid;              // 4608 float4 total
            float4 v = make_float4(0.f, 0.f, 0.f, 0.f);
            if (base4 + f >= 0) v = u4[base4 + f];
            int r  = f >> 4;                    // LDS row
            int cb = (f & 15) * 8;              // col byte (8 B granule, bit3 safe)
            short4v pk;
            pk[0] = (short)f2bf(v.x); pk[1] = (short)f2bf(v.y);
            pk[2] = (short)f2bf(v.z); pk[3] = (short)f2bf(v.w);
            *(short4v*)(uS + (r * 128 + (cb ^ ((r & 7) << 4)))) = pk;
        }
    }
    __syncthreads();

    floatx4 acc[4][2];
#pragma unroll
    for (int mt = 0; mt < 4; ++mt)
#pragma unroll
        for (int nt = 0; nt < 2; ++nt) acc[mt][nt] = (floatx4){0.f, 0.f, 0.f, 0.f};

    // b-frag loader for tap pair {j, j+16}
    auto loadG2 = [&](short8 (&c0)[2][2], short8 (&c1)[2][2], int j) {
#pragma unroll
        for (int kb = 0; kb < 2; ++kb)
#pragma unroll
            for (int nt = 0; nt < 2; ++nt) {
                const size_t off = (size_t)(l15 + 16*(2*nhalf + nt))*64 + kb*32 + q*8;
                c1[kb][nt] = *(const short8*)(gG + (size_t)(j + 16)*4096 + off);
                c0[kb][nt] = *(const short8*)(gG + (size_t)j*4096 + off);
            }
    };
    // rt sweep for tap pair {j, j+16}: identical body to R2
    auto sweep = [&](const short8 (&c0)[2][2], const short8 (&c1)[2][2], int j) {
        const int swz  = ((l15 - j) & 7) << 4;
        const int rowb = (rg*64 + 16 - j + l15) * 128;
#pragma unroll
        for (int kb = 0; kb < 2; ++kb) {
            const int cb = (kb * 64 + q * 16) ^ swz;
#pragma unroll
            for (int rt = 0; rt <= 4; ++rt) {
                short8 a = *(const short8*)(uS + (rowb + rt * 2048 + cb));
                if (rt >= 1) {                  // tap j,   mt = rt-1
#pragma unroll
                    for (int nt = 0; nt < 2; ++nt)
                        acc[rt-1][nt] = __builtin_amdgcn_mfma_f32_16x16x32_bf16(
                            a, c0[kb][nt], acc[rt-1][nt], 0, 0, 0);
                }
                if (rt <= 3) {                  // tap j+16, mt = rt
#pragma unroll
                    for (int nt = 0; nt < 2; ++nt)
                        acc[rt][nt] = __builtin_amdgcn_mfma_f32_16x16x32_bf16(
                            a, c1[kb][nt], acc[rt][nt], 0, 0, 0);
                }
            }
        }
    };

    // software-pipelined main loop: two static buffer sets, unroll-2 over j
    short8 bA0[2][2], bA1[2][2], bB0[2][2], bB1[2][2];
    loadG2(bA0, bA1, 0);
#pragma unroll 1
    for (int jj = 0; jj < 8; ++jj) {
        loadG2(bB0, bB1, 2*jj + 1);         // prefetch j+1 (hidden under sweep j)
        sweep(bA0, bA1, 2*jj);
        if (jj < 7) loadG2(bA0, bA1, 2*jj + 2);  // prefetch j+2
        sweep(bB0, bB1, 2*jj + 1);
    }

    // tail: tap 32 (LDS row = rg*64 + 16mt + l15)
    {
        short8 bt[2][2];
#pragma unroll
        for (int kb = 0; kb < 2; ++kb)
#pragma unroll
            for (int nt = 0; nt < 2; ++nt)
                bt[kb][nt] = *(const short8*)(gG + (size_t)32*4096
                                  + (size_t)(l15 + 16*(2*nhalf + nt))*64 + kb*32 + q*8);
        const int swz  = (l15 & 7) << 4;
        const int rowb = (rg*64 + l15) * 128;
#pragma unroll
        for (int kb = 0; kb < 2; ++kb) {
            const int cb = (kb * 64 + q * 16) ^ swz;
#pragma unroll
            for (int mt = 0; mt < 4; ++mt) {
                short8 a = *(const short8*)(uS + (rowb + mt * 2048 + cb));
#pragma unroll
                for (int nt = 0; nt < 2; ++nt)
                    acc[mt][nt] = __builtin_amdgcn_mfma_f32_16x16x32_bf16(
                        a, bt[kb][nt], acc[mt][nt], 0, 0, 0);
            }
        }
    }

    // epilogue: row = rg*64 + 16mt + q*4 + r, col = 32*nhalf + 16nt + l15
    const bool zblk = (blockIdx.x == 0 && rg == 0);
#pragma unroll
    for (int mt = 0; mt < 4; ++mt)
#pragma unroll
        for (int nt = 0; nt < 2; ++nt) {
            const int p = l15 + 32*nhalf + 16*nt;
#pragma unroll
            for (int r = 0; r < 4; ++r) {
                int tl = rg*64 + mt*16 + q*4 + r;
                float v = acc[mt][nt][r];
                if (zblk && mt < 3) v += gZ[(mt*16 + q*4 + r)*64 + p];  // t < 48
                out[(size_t)(t0 + tl)*64 + p] = v;
            }
        }
}

extern "C" void kernel_launch(void* const* d_in, const int* in_sizes, int n_in,
                              void* d_out, int out_size, void* d_ws, size_t ws_size,
                              hipStream_t stream) {
    const float* u  = (const float*)d_in[0];
    const float* x0 = (const float*)d_in[1];
    const float* A  = (const float*)d_in[2];
    const float* B  = (const float*)d_in[3];
    const float* C  = (const float*)d_in[4];
    const float* D  = (const float*)d_in[5];
    float* out = (float*)d_out;

    unsigned short* gG = (unsigned short*)d_ws;                  // 33*4096 bf16 = 270 KB
    float* gZ = (float*)((char*)d_ws + 272384);                  // 48*64 fp32

    hipLaunchKernelGGL(k_prep, dim3(1), dim3(256), 0, stream,
                       A, B, C, D, x0, gG, gZ);
    hipLaunchKernelGGL(k_conv, dim3(T_LEN / ROWS), dim3(512), 0, stream,
                       u, gG, gZ, out);
}

// Round 4
// 238.281 us; speedup vs baseline: 1.1964x; 1.1723x over previous
//
#include <hip/hip_runtime.h>

// LinearRNN as truncated FIR convolution:
//   y_t = sum_{i=0}^{32} G_i u_{t-i} + C A^t x0,   G_0 = D, G_i = C A^{i-1} B.
// R6 (=R4 structural): 128-row waves + real register double-buffer for G.
//   R3's counters showed VGPR_Count=64 -> the (512,4) 128-reg cap made the
//   compiler sink the G prefetch to its use sites (pipeline compiled away).
//   Fix: ROWS=512, wave tile 128x32 (8 mt), 1 block/CU, launch_bounds(512,2)
//   -> 256-reg budget, dbuf fits (acc 64 + 2x32 b-frags + temps ~ 180).
//   Also halves per-FLOP G L2 traffic (was 88% of L2 ceiling at the MFMA
//   floor) and drops LDS-instr pressure to ~68% of matrix time.
//   Sweep body / tap pairing / XOR swizzle (0 conflicts) / k_prep: UNCHANGED.

#define T_LEN  262144
#define NTAP   33      // taps 0..32
#define ZLEN   48      // x0-correction horizon
#define ROWS   512     // output rows per conv block
#define HALO   32

typedef __attribute__((ext_vector_type(8))) short  short8;
typedef __attribute__((ext_vector_type(4))) short  short4v;
typedef __attribute__((ext_vector_type(4))) float  floatx4;

static __device__ __forceinline__ unsigned short f2bf(float f) {
    unsigned int x = __float_as_uint(f);
    x += 0x7fffu + ((x >> 16) & 1u);     // RNE (finite normals)
    return (unsigned short)(x >> 16);
}
static __device__ __forceinline__ float bf2f(unsigned short u) {
    return __uint_as_float(((unsigned int)u) << 16);
}

// ---------------------------------------------------------------------------
// K1: log-depth prep, UNCHANGED from R2/R3 (passed, absmax 0.094).
// pool slots: 0:An 1:At 2:Bt 3:E2n 4:E2t 5:E4t 6..9: M0..M3 (chain ping)
// ---------------------------------------------------------------------------
__global__ __launch_bounds__(256, 1) void k_prep(
    const float* __restrict__ A, const float* __restrict__ B,
    const float* __restrict__ C, const float* __restrict__ D,
    const float* __restrict__ x0, unsigned short* __restrict__ gG,
    float* __restrict__ gZ)
{
    __shared__ unsigned short pool[10][64][72];   // 92,160 B
    const int tid = threadIdx.x;
    const int wv = tid >> 6, lane = tid & 63, l15 = lane & 15, q = lane >> 4;

#pragma unroll
    for (int e = 0; e < 16; ++e) {
        int f = e * 256 + tid;
        int r = f >> 6, c = f & 63;
        unsigned short av = f2bf(A[f]);
        pool[0][r][c] = av;                // An
        pool[1][c][r] = av;                // At
        pool[2][c][r] = f2bf(B[f]);        // Bt
        pool[6][r][c] = f2bf(C[f]);        // M0 = C
        gG[f]         = f2bf(D[f]);        // G_0 = D
    }
    __syncthreads();

    float x0v[4];
#pragma unroll
    for (int nt = 0; nt < 4; ++nt) x0v[nt] = x0[l15 + 16 * nt];

    // phase 2: A2 = A*A, M1 = C*A
    {
        short8 bA[2][4];
#pragma unroll
        for (int kb = 0; kb < 2; ++kb)
#pragma unroll
            for (int nt = 0; nt < 4; ++nt)
                bA[kb][nt] = *(const short8*)&pool[1][l15 + 16*nt][kb*32 + q*8];

        short8 a0 = *(const short8*)&pool[0][16*wv + l15][q*8];
        short8 a1 = *(const short8*)&pool[0][16*wv + l15][32 + q*8];
#pragma unroll
        for (int nt = 0; nt < 4; ++nt) {
            floatx4 m = (floatx4){0.f, 0.f, 0.f, 0.f};
            m = __builtin_amdgcn_mfma_f32_16x16x32_bf16(a0, bA[0][nt], m, 0, 0, 0);
            m = __builtin_amdgcn_mfma_f32_16x16x32_bf16(a1, bA[1][nt], m, 0, 0, 0);
#pragma unroll
            for (int r = 0; r < 4; ++r) {
                unsigned short h = f2bf(m[r]);
                pool[3][16*wv + q*4 + r][l15 + 16*nt] = h;   // E2n
                pool[4][l15 + 16*nt][16*wv + q*4 + r] = h;   // E2t
            }
        }
        a0 = *(const short8*)&pool[6][16*wv + l15][q*8];
        a1 = *(const short8*)&pool[6][16*wv + l15][32 + q*8];
#pragma unroll
        for (int nt = 0; nt < 4; ++nt) {
            floatx4 m = (floatx4){0.f, 0.f, 0.f, 0.f};
            m = __builtin_amdgcn_mfma_f32_16x16x32_bf16(a0, bA[0][nt], m, 0, 0, 0);
            m = __builtin_amdgcn_mfma_f32_16x16x32_bf16(a1, bA[1][nt], m, 0, 0, 0);
#pragma unroll
            for (int r = 0; r < 4; ++r)
                pool[7][16*wv + q*4 + r][l15 + 16*nt] = f2bf(m[r]);   // M1
        }
    }
    __syncthreads();

    // phase 3: E4t = (A2*A2)^T slice; M2 = C*A2; M3 = M1*A2
    {
        short8 bA2[2][4];
#pragma unroll
        for (int kb = 0; kb < 2; ++kb)
#pragma unroll
            for (int nt = 0; nt < 4; ++nt)
                bA2[kb][nt] = *(const short8*)&pool[4][l15 + 16*nt][kb*32 + q*8];

        short8 a0 = *(const short8*)&pool[3][16*wv + l15][q*8];
        short8 a1 = *(const short8*)&pool[3][16*wv + l15][32 + q*8];
#pragma unroll
        for (int nt = 0; nt < 4; ++nt) {
            floatx4 m = (floatx4){0.f, 0.f, 0.f, 0.f};
            m = __builtin_amdgcn_mfma_f32_16x16x32_bf16(a0, bA2[0][nt], m, 0, 0, 0);
            m = __builtin_amdgcn_mfma_f32_16x16x32_bf16(a1, bA2[1][nt], m, 0, 0, 0);
#pragma unroll
            for (int r = 0; r < 4; ++r)
                pool[5][l15 + 16*nt][16*wv + q*4 + r] = f2bf(m[r]);   // E4t
        }
        a0 = *(const short8*)&pool[6][16*wv + l15][q*8];
        a1 = *(const short8*)&pool[6][16*wv + l15][32 + q*8];
#pragma unroll
        for (int nt = 0; nt < 4; ++nt) {
            floatx4 m = (floatx4){0.f, 0.f, 0.f, 0.f};
            m = __builtin_amdgcn_mfma_f32_16x16x32_bf16(a0, bA2[0][nt], m, 0, 0, 0);
            m = __builtin_amdgcn_mfma_f32_16x16x32_bf16(a1, bA2[1][nt], m, 0, 0, 0);
#pragma unroll
            for (int r = 0; r < 4; ++r)
                pool[8][16*wv + q*4 + r][l15 + 16*nt] = f2bf(m[r]);   // M2
        }
        a0 = *(const short8*)&pool[7][16*wv + l15][q*8];
        a1 = *(const short8*)&pool[7][16*wv + l15][32 + q*8];
#pragma unroll
        for (int nt = 0; nt < 4; ++nt) {
            floatx4 m = (floatx4){0.f, 0.f, 0.f, 0.f};
            m = __builtin_amdgcn_mfma_f32_16x16x32_bf16(a0, bA2[0][nt], m, 0, 0, 0);
            m = __builtin_amdgcn_mfma_f32_16x16x32_bf16(a1, bA2[1][nt], m, 0, 0, 0);
#pragma unroll
            for (int r = 0; r < 4; ++r)
                pool[9][16*wv + q*4 + r][l15 + 16*nt] = f2bf(m[r]);   // M3
        }
    }
    __syncthreads();

    short8 bE[2][4], bB[2][4];
#pragma unroll
    for (int kb = 0; kb < 2; ++kb)
#pragma unroll
        for (int nt = 0; nt < 4; ++nt) {
            bE[kb][nt] = *(const short8*)&pool[5][l15 + 16*nt][kb*32 + q*8];
            bB[kb][nt] = *(const short8*)&pool[2][l15 + 16*nt][kb*32 + q*8];
        }
    __syncthreads();   // pool[0..4] now reusable as chain pong buffers

    unsigned short (*cur)[72] = pool[6 + wv];
    unsigned short (*alt)[72] = pool[wv];

#pragma unroll
    for (int mt = 0; mt < 4; ++mt)
#pragma unroll
        for (int r = 0; r < 4; ++r) {
            float v = 0.f;
#pragma unroll
            for (int nt = 0; nt < 4; ++nt)
                v += bf2f(cur[16*mt + q*4 + r][l15 + 16*nt]) * x0v[nt];
            v += __shfl_xor(v, 1, 16); v += __shfl_xor(v, 2, 16);
            v += __shfl_xor(v, 4, 16); v += __shfl_xor(v, 8, 16);
            if (l15 == 0) gZ[wv*64 + 16*mt + q*4 + r] = v;
        }

    for (int k = 1; k <= 11; ++k) {
        const int jm = 4*(k-1) + wv;     // cur = M_jm
        short8 a0[4], a1[4];
#pragma unroll
        for (int mt = 0; mt < 4; ++mt) {
            a0[mt] = *(const short8*)&cur[16*mt + l15][q*8];
            a1[mt] = *(const short8*)&cur[16*mt + l15][32 + q*8];
        }
        if (jm < 32) {                   // G_{jm+1} = M_jm * B
#pragma unroll
            for (int mt = 0; mt < 4; ++mt)
#pragma unroll
                for (int nt = 0; nt < 4; ++nt) {
                    floatx4 g = (floatx4){0.f, 0.f, 0.f, 0.f};
                    g = __builtin_amdgcn_mfma_f32_16x16x32_bf16(a0[mt], bB[0][nt], g, 0, 0, 0);
                    g = __builtin_amdgcn_mfma_f32_16x16x32_bf16(a1[mt], bB[1][nt], g, 0, 0, 0);
#pragma unroll
                    for (int r = 0; r < 4; ++r)
                        gG[(size_t)(jm+1)*4096 + (16*mt + q*4 + r)*64 + l15 + 16*nt] = f2bf(g[r]);
                }
        }
        floatx4 m[4][4];
#pragma unroll
        for (int mt = 0; mt < 4; ++mt)
#pragma unroll
            for (int nt = 0; nt < 4; ++nt) {
                m[mt][nt] = (floatx4){0.f, 0.f, 0.f, 0.f};
                m[mt][nt] = __builtin_amdgcn_mfma_f32_16x16x32_bf16(a0[mt], bE[0][nt], m[mt][nt], 0, 0, 0);
                m[mt][nt] = __builtin_amdgcn_mfma_f32_16x16x32_bf16(a1[mt], bE[1][nt], m[mt][nt], 0, 0, 0);
            }
#pragma unroll
        for (int mt = 0; mt < 4; ++mt)
#pragma unroll
            for (int nt = 0; nt < 4; ++nt)
#pragma unroll
                for (int r = 0; r < 4; ++r)
                    alt[16*mt + q*4 + r][l15 + 16*nt] = f2bf(m[mt][nt][r]);
        const int zi = 4*k + wv;
#pragma unroll
        for (int mt = 0; mt < 4; ++mt)
#pragma unroll
            for (int r = 0; r < 4; ++r) {
                float v = 0.f;
#pragma unroll
                for (int nt = 0; nt < 4; ++nt) v = fmaf(m[mt][nt][r], x0v[nt], v);
                v += __shfl_xor(v, 1, 16); v += __shfl_xor(v, 2, 16);
                v += __shfl_xor(v, 4, 16); v += __shfl_xor(v, 8, 16);
                if (l15 == 0) gZ[zi*64 + 16*mt + q*4 + r] = v;
            }
        unsigned short (*tmp)[72] = cur; cur = alt; alt = tmp;
    }
}

// ---------------------------------------------------------------------------
// K2 v4: 128x32 wave tiles + surviving G double-buffer.
// 512 thr = 8 waves; rg=w>>1 owns 128 rows (8 mt), nhalf=w&1 owns 32 cols.
// acc[8 mt][2 nt] = 64 AGPR; 2 b-frag buffer sets = 64 VGPR; budget 256
// via __launch_bounds__(512,2). LDS = uS only (69.6 KB), 1 block/CU,
// no barriers after staging. Tap pairing + XOR swizzle unchanged.
// Per wave: 1056 MFMA, 304 ds_read_b128, 16 j-pair G loads (8 KB each).
// ---------------------------------------------------------------------------
__global__ __launch_bounds__(512, 2) void k_conv(
    const float* __restrict__ u, const unsigned short* __restrict__ gG,
    const float* __restrict__ gZ, float* __restrict__ out)
{
    __shared__ __align__(16) unsigned char uS[(ROWS + HALO) * 128];  // 69,632 B
    const int tid = threadIdx.x;
    const int wv = tid >> 6, lane = tid & 63, l15 = lane & 15, q = lane >> 4;
    const int nhalf = wv & 1, rg = wv >> 1;
    const int t0 = blockIdx.x * ROWS;

    // stage u rows [t0-32, t0+512) as bf16 (rows < 0 -> zeros, block 0 only)
    {
        const float4* u4 = (const float4*)u;
        const int base4 = (t0 - HALO) * 16;     // float4 index of first staged row
#pragma unroll
        for (int e = 0; e < 17; ++e) {
            int f = e * 512 + tid;              // 8704 float4 total
            float4 v = make_float4(0.f, 0.f, 0.f, 0.f);
            if (base4 + f >= 0) v = u4[base4 + f];
            int r  = f >> 4;                    // LDS row
            int cb = (f & 15) * 8;              // col byte (8 B granule, bit3 safe)
            short4v pk;
            pk[0] = (short)f2bf(v.x); pk[1] = (short)f2bf(v.y);
            pk[2] = (short)f2bf(v.z); pk[3] = (short)f2bf(v.w);
            *(short4v*)(uS + (r * 128 + (cb ^ ((r & 7) << 4)))) = pk;
        }
    }
    __syncthreads();

    floatx4 acc[8][2];
#pragma unroll
    for (int mt = 0; mt < 8; ++mt)
#pragma unroll
        for (int nt = 0; nt < 2; ++nt) acc[mt][nt] = (floatx4){0.f, 0.f, 0.f, 0.f};

    // b-frag loader for tap pair {j, j+16}
    auto loadG2 = [&](short8 (&c0)[2][2], short8 (&c1)[2][2], int j) {
#pragma unroll
        for (int kb = 0; kb < 2; ++kb)
#pragma unroll
            for (int nt = 0; nt < 2; ++nt) {
                const size_t off = (size_t)(l15 + 16*(2*nhalf + nt))*64 + kb*32 + q*8;
                c1[kb][nt] = *(const short8*)(gG + (size_t)(j + 16)*4096 + off);
                c0[kb][nt] = *(const short8*)(gG + (size_t)j*4096 + off);
            }
    };
    // rt sweep for tap pair {j, j+16}: read rt feeds tap j at mt=rt-1 and
    // tap j+16 at mt=rt.  LDS row = rg*128 + 16*rt + 16 - j + l15.
    auto sweep = [&](const short8 (&c0)[2][2], const short8 (&c1)[2][2], int j) {
        const int swz  = ((l15 - j) & 7) << 4;
        const int rowb = (rg*128 + 16 - j + l15) * 128;
#pragma unroll
        for (int kb = 0; kb < 2; ++kb) {
            const int cb = (kb * 64 + q * 16) ^ swz;
#pragma unroll
            for (int rt = 0; rt <= 8; ++rt) {
                short8 a = *(const short8*)(uS + (rowb + rt * 2048 + cb));
                if (rt >= 1) {                  // tap j,   mt = rt-1
#pragma unroll
                    for (int nt = 0; nt < 2; ++nt)
                        acc[rt-1][nt] = __builtin_amdgcn_mfma_f32_16x16x32_bf16(
                            a, c0[kb][nt], acc[rt-1][nt], 0, 0, 0);
                }
                if (rt <= 7) {                  // tap j+16, mt = rt
#pragma unroll
                    for (int nt = 0; nt < 2; ++nt)
                        acc[rt][nt] = __builtin_amdgcn_mfma_f32_16x16x32_bf16(
                            a, c1[kb][nt], acc[rt][nt], 0, 0, 0);
                }
            }
        }
    };

    // software-pipelined main loop: two static buffer sets, unroll-2 over j
    short8 bA0[2][2], bA1[2][2], bB0[2][2], bB1[2][2];
    loadG2(bA0, bA1, 0);
#pragma unroll 1
    for (int jj = 0; jj < 8; ++jj) {
        loadG2(bB0, bB1, 2*jj + 1);         // prefetch j+1 (hidden under sweep j)
        sweep(bA0, bA1, 2*jj);
        if (jj < 7) loadG2(bA0, bA1, 2*jj + 2);  // prefetch j+2
        sweep(bB0, bB1, 2*jj + 1);
    }

    // tail: tap 32 (LDS row = rg*128 + 16mt + l15)
    {
        short8 bt[2][2];
#pragma unroll
        for (int kb = 0; kb < 2; ++kb)
#pragma unroll
            for (int nt = 0; nt < 2; ++nt)
                bt[kb][nt] = *(const short8*)(gG + (size_t)32*4096
                                  + (size_t)(l15 + 16*(2*nhalf + nt))*64 + kb*32 + q*8);
        const int swz  = (l15 & 7) << 4;
        const int rowb = (rg*128 + l15) * 128;
#pragma unroll
        for (int kb = 0; kb < 2; ++kb) {
            const int cb = (kb * 64 + q * 16) ^ swz;
#pragma unroll
            for (int mt = 0; mt < 8; ++mt) {
                short8 a = *(const short8*)(uS + (rowb + mt * 2048 + cb));
#pragma unroll
                for (int nt = 0; nt < 2; ++nt)
                    acc[mt][nt] = __builtin_amdgcn_mfma_f32_16x16x32_bf16(
                        a, bt[kb][nt], acc[mt][nt], 0, 0, 0);
            }
        }
    }

    // epilogue: row = rg*128 + 16mt + q*4 + r, col = 32*nhalf + 16nt + l15
    const bool zblk = (blockIdx.x == 0 && rg == 0);
#pragma unroll
    for (int mt = 0; mt < 8; ++mt)
#pragma unroll
        for (int nt = 0; nt < 2; ++nt) {
            const int p = l15 + 32*nhalf + 16*nt;
#pragma unroll
            for (int r = 0; r < 4; ++r) {
                int tl = rg*128 + mt*16 + q*4 + r;
                float v = acc[mt][nt][r];
                if (zblk && mt < 3) v += gZ[(mt*16 + q*4 + r)*64 + p];  // t < 48
                out[(size_t)(t0 + tl)*64 + p] = v;
            }
        }
}

extern "C" void kernel_launch(void* const* d_in, const int* in_sizes, int n_in,
                              void* d_out, int out_size, void* d_ws, size_t ws_size,
                              hipStream_t stream) {
    const float* u  = (const float*)d_in[0];
    const float* x0 = (const float*)d_in[1];
    const float* A  = (const float*)d_in[2];
    const float* B  = (const float*)d_in[3];
    const float* C  = (const float*)d_in[4];
    const float* D  = (const float*)d_in[5];
    float* out = (float*)d_out;

    unsigned short* gG = (unsigned short*)d_ws;                  // 33*4096 bf16 = 270 KB
    float* gZ = (float*)((char*)d_ws + 272384);                  // 48*64 fp32

    hipLaunchKernelGGL(k_prep, dim3(1), dim3(256), 0, stream,
                       A, B, C, D, x0, gG, gZ);
    hipLaunchKernelGGL(k_conv, dim3(T_LEN / ROWS), dim3(512), 0, stream,
                       u, gG, gZ, out);
}